// Round 8
// baseline (136.025 us; speedup 1.0000x reference)
//
#include <hip/hip_runtime.h>
#include <hip/hip_bf16.h>
#include <math.h>

#define T_SEQ 4096
#define NBATCH 4
#define C_EMB 512
#define HEAD 64
#define CHUNK 8                  // k-tiles (of 64) per attn phase-1 block
#define EPB 288                  // per batch: sum over qt of ceil((qt+1)/8)

typedef __attribute__((ext_vector_type(8))) short short8;
typedef __attribute__((ext_vector_type(4))) short short4v;
typedef __attribute__((ext_vector_type(4))) float f32x4;

// scale folded into q at projection: exp(s/sqrt(512)) = exp2(qhat . k)
#define C2 (0.044194173824159216f * 1.44269504088896340736f)

__device__ __forceinline__ unsigned short f2bf(float f) {
    union { float f; unsigned u; } v; v.f = f;
    unsigned u = v.u;
    u += 0x7FFF + ((u >> 16) & 1);   // round-to-nearest-even
    return (unsigned short)(u >> 16);
}
// packed f32x2 -> bf16x2 (v_cvt_pk_bf16_f32); low 16 = a, high 16 = b
__device__ __forceinline__ unsigned pk2bf(float a, float b) {
    __hip_bfloat162 h = __float22bfloat162_rn(make_float2(a, b));
    return *(unsigned*)&h;
}
__device__ __forceinline__ float bf2f(unsigned short u) {
    union { unsigned u; float f; } v; v.u = ((unsigned)u) << 16;
    return v.f;
}

// ---------------- W conversion: Wt[g][k] bf16 = W[k][n], g = w*4tiles ----------
__global__ __launch_bounds__(64) void wcvt_kernel(
    const float* __restrict__ Wq, const float* __restrict__ Wk,
    const float* __restrict__ Wv, unsigned short* __restrict__ wt)
{
    const int w = blockIdx.x >> 6;
    const int n = blockIdx.x & 63;
    const float* W = (w == 0) ? Wq : (w == 1) ? Wk : Wv;
    const int k0 = threadIdx.x * 8;
    unsigned short tmp[8];
#pragma unroll
    for (int i = 0; i < 8; ++i) tmp[i] = f2bf(W[(size_t)(k0 + i) * HEAD + n]);
    *(short8*)(wt + ((size_t)blockIdx.x) * C_EMB + k0) = *(short8*)tmp;
}

// ---------------- Projection: column-split waves, 2 blocks/CU ----------------
// grid 512 x 256; block owns 32 rows. Waves 0,1 (wgroup0): Wq(4 tiles)+Wk(n0,1).
// Waves 2,3 (wgroup1): Wk(n2,3)+Wv(4 tiles). Global tile id g = wgroup*6+j maps
// to wt row g*16. Waves 0/2 (1/3) read the same x rows -> L1 reuse.
__device__ __forceinline__ void ld_stage(const float* xp, int s, float4* xr) {
#pragma unroll
    for (int j = 0; j < 4; ++j) {
        xr[2 * j]     = *(const float4*)(xp + (s * 4 + j) * 32);
        xr[2 * j + 1] = *(const float4*)(xp + (s * 4 + j) * 32 + 4);
    }
}

__device__ __forceinline__ void mm_stage(const float4* xr, int s, int l16, int quad,
                                         int gbase,
                                         const unsigned short* __restrict__ wt,
                                         f32x4 acc[6]) {
#pragma unroll
    for (int j = 0; j < 4; ++j) {
        const int kc = s * 4 + j;
        float4 a = xr[2 * j], b = xr[2 * j + 1];
        int4 ai = make_int4((int)pk2bf(a.x, a.y), (int)pk2bf(a.z, a.w),
                            (int)pk2bf(b.x, b.y), (int)pk2bf(b.z, b.w));
        short8 af = *(short8*)&ai;
#pragma unroll
        for (int t = 0; t < 6; ++t) {
            short8 bf = *(const short8*)(wt + ((size_t)((gbase + t) * 16 + l16)) * C_EMB
                                            + kc * 32 + quad * 8);
            acc[t] = __builtin_amdgcn_mfma_f32_16x16x32_bf16(af, bf, acc[t], 0, 0, 0);
        }
    }
}

__global__ __launch_bounds__(256, 2) void proj_kernel(
    const float* __restrict__ x,            // [16384, 512]
    const unsigned short* __restrict__ wt,  // [12][16][512] bf16 tiles
    unsigned short* __restrict__ qout,      // [16384, 64]  (pre-scaled by C2)
    unsigned short* __restrict__ kout,      // [16384, 64]
    unsigned short* __restrict__ vt)        // [4][64][4096]
{
    __shared__ unsigned short Vsh[64][40];  // [h][trow 0..31, +8 pad]

    const int tid    = threadIdx.x;
    const int wave   = tid >> 6;
    const int lane   = tid & 63;
    const int l16    = lane & 15;
    const int quad   = lane >> 4;
    const int rowblk = wave & 1;
    const int wgroup = wave >> 1;
    const int gbase  = wgroup * 6;
    const int row0   = blockIdx.x * 32;
    const int rowW   = row0 + rowblk * 16 + l16;

    f32x4 acc[6];
#pragma unroll
    for (int t = 0; t < 6; ++t) acc[t] = (f32x4){0.f, 0.f, 0.f, 0.f};

    const float* xp = x + (size_t)rowW * C_EMB + quad * 8;
    float4 xr[2][8];
    ld_stage(xp, 0, xr[0]);
#pragma unroll
    for (int s = 0; s < 4; ++s) {
        if (s < 3) ld_stage(xp, s + 1, xr[(s + 1) & 1]);
        mm_stage(xr[s & 1], s, l16, quad, gbase, wt, acc);
    }

    // epilogue: C layout row = quad*4+r, col = l16 within each 16-col tile
#pragma unroll
    for (int r = 0; r < 4; ++r) {
        const int row = row0 + rowblk * 16 + quad * 4 + r;
        if (wgroup == 0) {
#pragma unroll
            for (int j = 0; j < 4; ++j)
                qout[(size_t)row * HEAD + j * 16 + l16] = f2bf(acc[j][r] * C2);
            kout[(size_t)row * HEAD + 0 * 16 + l16] = f2bf(acc[4][r]);
            kout[(size_t)row * HEAD + 1 * 16 + l16] = f2bf(acc[5][r]);
        } else {
            kout[(size_t)row * HEAD + 2 * 16 + l16] = f2bf(acc[0][r]);
            kout[(size_t)row * HEAD + 3 * 16 + l16] = f2bf(acc[1][r]);
#pragma unroll
            for (int j = 2; j < 6; ++j)
                Vsh[(j - 2) * 16 + l16][rowblk * 16 + quad * 4 + r] = f2bf(acc[j][r]);
        }
    }
    __syncthreads();
    {
        int h  = tid >> 2;
        int tc = (tid & 3) * 8;
        int b  = row0 >> 12;
        int t0 = row0 & (T_SEQ - 1);
        unsigned short* dst = vt + ((size_t)(b * HEAD + h)) * T_SEQ + t0 + tc;
        *(short8*)dst = *(const short8*)&Vsh[h][tc];
    }
}

// stage one V row-chunk (16 cols from sc) phi-swizzled:
// col c bits [s|d|q1 q0|r1 r0] -> position [s|q1 q0|d|r1 r0]
// so PV B-frags are single contiguous b128 reads matching the A-frag k-order.
__device__ __forceinline__ void stage_v(unsigned short (*Vbuf)[72], int sr, int phiA,
                                        short8 v0, short8 v1) {
    *(short4v*)&Vbuf[sr][phiA]      = __builtin_shufflevector(v0, v0, 0, 1, 2, 3);
    *(short4v*)&Vbuf[sr][phiA + 8]  = __builtin_shufflevector(v0, v0, 4, 5, 6, 7);
    *(short4v*)&Vbuf[sr][phiA + 16] = __builtin_shufflevector(v1, v1, 0, 1, 2, 3);
    *(short4v*)&Vbuf[sr][phiA + 24] = __builtin_shufflevector(v1, v1, 4, 5, 6, 7);
}

// ---------------- Attention phase 1: S^T trick, no P LDS round-trip ----------
__global__ __launch_bounds__(256) void attn1_kernel(
    const unsigned short* __restrict__ qb,  // [B*T, 64] pre-scaled
    const unsigned short* __restrict__ kb,  // [B*T, 64]
    const unsigned short* __restrict__ vt,  // [4][64][4096]
    unsigned short* __restrict__ po,        // [1152][64][64] bf16 partials
    float* __restrict__ pl)                 // [1152][64]
{
    __shared__ unsigned short Ks[2][64][72];    // [buf][kpos][h]
    __shared__ unsigned short Vs[2][64][72];    // [buf][h][phi(kpos)]

    const int tid  = threadIdx.x;
    const int wave = tid >> 6;
    const int lane = tid & 63;
    const int l16  = lane & 15;
    const int quad = lane >> 4;

    const int b = blockIdx.x / EPB;
    const int e = blockIdx.x % EPB;
    // decode e -> (qt, c): group g has qt in [8g,8g+8), nc=g+1, base 4g(g+1)
    int g = 0;
#pragma unroll
    for (int gg = 1; gg < 8; ++gg) if (e >= 4 * gg * (gg + 1)) g = gg;
    const int rem = e - 4 * g * (g + 1);
    const int t   = rem / (g + 1);
    const int c   = rem - t * (g + 1);
    const int qt  = 8 * g + t;

    const size_t base = (size_t)b * T_SEQ;
    const int qrow = qt * 64 + wave * 16 + l16;
    short8 aq0 = *(const short8*)(qb + (base + qrow) * HEAD + quad * 8);
    short8 aq1 = *(const short8*)(qb + (base + qrow) * HEAD + 32 + quad * 8);

    float lacc = 0.f;
    f32x4 o[4];
#pragma unroll
    for (int n = 0; n < 4; ++n) o[n] = (f32x4){0.f, 0.f, 0.f, 0.f};

    const int kt0 = c * CHUNK;
    const int np  = min(CHUNK, qt + 1 - kt0);   // 1..8 64-wide iterations

    const int sr   = tid >> 2;            // 0..63
    const int sc   = (tid & 3) * 16;      // 0,16,32,48
    const int phiA = (sc & 32) + ((sc & 16) >> 2);

    short8 kra, krb, vra, vrb;
    {
        const int kbase = kt0 * 64;
        const unsigned short* ksrc = kb + (base + kbase + sr) * HEAD + sc;
        const unsigned short* vsrc = vt + ((size_t)(b * HEAD + sr)) * T_SEQ + kbase + sc;
        kra = *(const short8*)(ksrc);     krb = *(const short8*)(ksrc + 8);
        vra = *(const short8*)(vsrc);     vrb = *(const short8*)(vsrc + 8);
    }
    *(short8*)&Ks[0][sr][sc]     = kra;  *(short8*)&Ks[0][sr][sc + 8] = krb;
    stage_v(Vs[0], sr, phiA, vra, vrb);

    for (int p = 0; p < np; ++p) {
        const int cur = p & 1;
        const int kbase = (kt0 + p) * 64;
        __syncthreads();                 // LDS[cur] ready; prev-iter reads done

        if (p + 1 < np) {                // prefetch next tile into regs
            const int nb = kbase + 64;
            const unsigned short* ksrc = kb + (base + nb + sr) * HEAD + sc;
            const unsigned short* vsrc = vt + ((size_t)(b * HEAD + sr)) * T_SEQ + nb + sc;
            kra = *(const short8*)(ksrc);  krb = *(const short8*)(ksrc + 8);
            vra = *(const short8*)(vsrc);  vrb = *(const short8*)(vsrc + 8);
        }

        // S^T = K.Q^T: lane gets S[q=l16][c = kbase + n*16 + quad*4 + r]
        f32x4 s[4];
#pragma unroll
        for (int n = 0; n < 4; ++n) {
            short8 bk0 = *(const short8*)&Ks[cur][n * 16 + l16][quad * 8];
            short8 bk1 = *(const short8*)&Ks[cur][n * 16 + l16][32 + quad * 8];
            f32x4 accS = (f32x4){0.f, 0.f, 0.f, 0.f};
            accS = __builtin_amdgcn_mfma_f32_16x16x32_bf16(bk0, aq0, accS, 0, 0, 0);
            accS = __builtin_amdgcn_mfma_f32_16x16x32_bf16(bk1, aq1, accS, 0, 0, 0);
            s[n] = accS;
        }

        // P = exp2(S); zero masked cols on the diagonal tile (wave-uniform test)
#pragma unroll
        for (int n = 0; n < 4; ++n)
#pragma unroll
            for (int r = 0; r < 4; ++r)
                s[n][r] = __builtin_amdgcn_exp2f(s[n][r]);

        if (kbase + 64 > qt * 64) {
            const int cb = kbase + quad * 4;
#pragma unroll
            for (int n = 0; n < 4; ++n)
#pragma unroll
                for (int r = 0; r < 4; ++r)
                    if (cb + n * 16 + r > qrow) s[n][r] = 0.f;
        }

#pragma unroll
        for (int n = 0; n < 4; ++n)
            lacc += (s[n][0] + s[n][1]) + (s[n][2] + s[n][3]);

        // PV: pack A-frag locally (k-order matches phi-swizzled V), B = b128
#pragma unroll
        for (int st = 0; st < 2; ++st) {
            int4 ai = make_int4(
                (int)pk2bf(s[2 * st][0],     s[2 * st][1]),
                (int)pk2bf(s[2 * st][2],     s[2 * st][3]),
                (int)pk2bf(s[2 * st + 1][0], s[2 * st + 1][1]),
                (int)pk2bf(s[2 * st + 1][2], s[2 * st + 1][3]));
            short8 af = *(short8*)&ai;
#pragma unroll
            for (int n = 0; n < 4; ++n) {
                short8 bv = *(const short8*)&Vs[cur][n * 16 + l16][32 * st + quad * 8];
                o[n] = __builtin_amdgcn_mfma_f32_16x16x32_bf16(af, bv, o[n], 0, 0, 0);
            }
        }

        if (p + 1 < np) {                // stage next tile into the other buffer
            const int nxt = cur ^ 1;
            *(short8*)&Ks[nxt][sr][sc]     = kra;  *(short8*)&Ks[nxt][sr][sc + 8] = krb;
            stage_v(Vs[nxt], sr, phiA, vra, vrb);
        }
    }

    // reduce l over the quad dimension (q-row = l16 per lane)
    lacc += __shfl_xor(lacc, 16);
    lacc += __shfl_xor(lacc, 32);

    const int pid = blockIdx.x;
#pragma unroll
    for (int n = 0; n < 4; ++n)
#pragma unroll
        for (int r = 0; r < 4; ++r) {
            int lr = wave * 16 + quad * 4 + r;
            po[(size_t)pid * 4096 + lr * 64 + n * 16 + l16] = f2bf(o[n][r]);
        }
    if (quad == 0)
        pl[pid * 64 + wave * 16 + l16] = lacc;
}

// ---------------- Combine: sum <=8 bf16 partials, normalize ----------------
// grid 512 x 256; thread owns 8 output cols (one short8 read per partial).
__global__ __launch_bounds__(256) void combine_kernel(
    const unsigned short* __restrict__ po, const float* __restrict__ pl,
    float* __restrict__ out)
{
    const int gth = blockIdx.x * 256 + threadIdx.x;   // octet index, 131072 total
    const int h8  = gth & 7;
    const int row = gth >> 3;
    const int lr  = row & 63;
    const int qt  = (row >> 6) & 63;
    const int b   = row >> 12;
    const int nc  = (qt >> 3) + 1;
    const int g   = qt >> 3;
    const int rem = qt & 7;
    const int e0  = 4 * g * (g + 1) + rem * (g + 1);
    const int pid0 = b * EPB + e0;

    float l = 0.f;
    float acc[8];
#pragma unroll
    for (int i = 0; i < 8; ++i) acc[i] = 0.f;
    for (int cc = 0; cc < nc; ++cc) {
        l += pl[(pid0 + cc) * 64 + lr];
        short8 p8 = *(const short8*)(po + (size_t)(pid0 + cc) * 4096 + lr * 64 + h8 * 8);
#pragma unroll
        for (int i = 0; i < 8; ++i) acc[i] += bf2f((unsigned short)p8[i]);
    }
    float inv = 1.f / l;
    float4 r0 = make_float4(acc[0] * inv, acc[1] * inv, acc[2] * inv, acc[3] * inv);
    float4 r1 = make_float4(acc[4] * inv, acc[5] * inv, acc[6] * inv, acc[7] * inv);
    float* dst = out + (size_t)gth * 8;
    *(float4*)dst       = r0;
    *(float4*)(dst + 4) = r1;
}

extern "C" void kernel_launch(void* const* d_in, const int* in_sizes, int n_in,
                              void* d_out, int out_size, void* d_ws, size_t ws_size,
                              hipStream_t stream) {
    const float* x  = (const float*)d_in[0];
    const float* Wq = (const float*)d_in[1];
    const float* Wk = (const float*)d_in[2];
    const float* Wv = (const float*)d_in[3];
    float* out = (float*)d_out;

    char* ws = (char*)d_ws;
    unsigned short* qb = (unsigned short*)(ws);                 // 2 MB
    unsigned short* kb = (unsigned short*)(ws + (2u << 20));    // 2 MB
    unsigned short* vt = (unsigned short*)(ws + (4u << 20));    // 2 MB
    unsigned short* wt = (unsigned short*)(ws + (6u << 20));    // 192 KB
    float* pl = (float*)(ws + (6u << 20) + 196608);             // 294912 B
    unsigned short* po = (unsigned short*)(ws + (6u << 20) + 196608 + 294912); // 9.4 MB

    wcvt_kernel<<<dim3(192), dim3(64), 0, stream>>>(Wq, Wk, Wv, wt);
    proj_kernel<<<dim3(512), dim3(256), 0, stream>>>(x, wt, qb, kb, vt);
    attn1_kernel<<<dim3(NBATCH * EPB), dim3(256), 0, stream>>>(qb, kb, vt, po, pl);
    combine_kernel<<<dim3(512), dim3(256), 0, stream>>>(po, pl, out);
}

// Round 9
// 133.667 us; speedup vs baseline: 1.0176x; 1.0176x over previous
//
#include <hip/hip_runtime.h>
#include <hip/hip_bf16.h>
#include <math.h>

#define T_SEQ 4096
#define NBATCH 4
#define C_EMB 512
#define HEAD 64
#define CHUNK 8                  // k-tiles (of 64) per attn phase-1 block
#define EPB 288                  // per batch: sum over qt of ceil((qt+1)/8)

typedef __attribute__((ext_vector_type(8))) short short8;
typedef __attribute__((ext_vector_type(4))) short short4v;
typedef __attribute__((ext_vector_type(4))) float f32x4;

// scale folded into q at projection: exp(s/sqrt(512)) = exp2(qhat . k)
#define C2 (0.044194173824159216f * 1.44269504088896340736f)

__device__ __forceinline__ unsigned short f2bf(float f) {
    union { float f; unsigned u; } v; v.f = f;
    unsigned u = v.u;
    u += 0x7FFF + ((u >> 16) & 1);   // round-to-nearest-even
    return (unsigned short)(u >> 16);
}
// packed f32x2 -> bf16x2 (v_cvt_pk_bf16_f32); low 16 = a, high 16 = b
__device__ __forceinline__ unsigned pk2bf(float a, float b) {
    __hip_bfloat162 h = __float22bfloat162_rn(make_float2(a, b));
    return *(unsigned*)&h;
}
__device__ __forceinline__ float bf2f(unsigned short u) {
    union { unsigned u; float f; } v; v.u = ((unsigned)u) << 16;
    return v.f;
}

// ---------------- W conversion: wt[w*64+n][k] bf16 = W[k][n] ----------------
__global__ __launch_bounds__(64) void wcvt_kernel(
    const float* __restrict__ Wq, const float* __restrict__ Wk,
    const float* __restrict__ Wv, unsigned short* __restrict__ wt)
{
    const int w = blockIdx.x >> 6;
    const int n = blockIdx.x & 63;
    const float* W = (w == 0) ? Wq : (w == 1) ? Wk : Wv;
    const int k0 = threadIdx.x * 8;
    unsigned short tmp[8];
#pragma unroll
    for (int i = 0; i < 8; ++i) tmp[i] = f2bf(W[(size_t)(k0 + i) * HEAD + n]);
    *(short8*)(wt + ((size_t)blockIdx.x) * C_EMB + k0) = *(short8*)tmp;
}

// ---------------- Projection: K-split waves (2 waves/SIMD), LDS-free MFMA ----
// grid 512 x 256; block owns 32 rows. Waves {0,1}: K 0..255; waves {2,3}:
// K 256..511 (same rows, disjoint K -> NO duplicated x/W traffic). Partial
// accs merged via LDS, then q/k row-major stores + V transpose -> vt[b][h][t].
__device__ __forceinline__ void ld_stage(const float* xp, int s, float4* xr) {
#pragma unroll
    for (int j = 0; j < 4; ++j) {
        xr[2 * j]     = *(const float4*)(xp + (s * 4 + j) * 32);
        xr[2 * j + 1] = *(const float4*)(xp + (s * 4 + j) * 32 + 4);
    }
}

__device__ __forceinline__ void mm_stage(const float4* xr, int kb, int s,
                                         int l16, int quad,
                                         const unsigned short* __restrict__ wt,
                                         f32x4 acc[12]) {
#pragma unroll
    for (int j = 0; j < 4; ++j) {
        const int kc = kb + s * 4 + j;
        float4 a = xr[2 * j], b = xr[2 * j + 1];
        int4 ai = make_int4((int)pk2bf(a.x, a.y), (int)pk2bf(a.z, a.w),
                            (int)pk2bf(b.x, b.y), (int)pk2bf(b.z, b.w));
        short8 af = *(short8*)&ai;
#pragma unroll
        for (int t = 0; t < 12; ++t) {
            short8 bf = *(const short8*)(wt + ((size_t)(t * 16 + l16)) * C_EMB
                                            + kc * 32 + quad * 8);
            acc[t] = __builtin_amdgcn_mfma_f32_16x16x32_bf16(af, bf, acc[t], 0, 0, 0);
        }
    }
}

__global__ __launch_bounds__(256) void proj_kernel(
    const float* __restrict__ x,            // [16384, 512]
    const unsigned short* __restrict__ wt,  // [192][512] bf16 (w*64+n rows)
    unsigned short* __restrict__ qout,      // [16384, 64]  (pre-scaled by C2)
    unsigned short* __restrict__ kout,      // [16384, 64]
    unsigned short* __restrict__ vt)        // [4][64][4096]
{
    __shared__ f32x4 Red[2][12][64];        // 24 KB partial-acc merge
    __shared__ unsigned short Vsh[64][40];  // [h][trow 0..31, +8 pad]

    const int tid    = threadIdx.x;
    const int wave   = tid >> 6;
    const int lane   = tid & 63;
    const int l16    = lane & 15;
    const int quad   = lane >> 4;
    const int rowblk = wave & 1;
    const int khalf  = wave >> 1;
    const int row0   = blockIdx.x * 32;
    const int rowW   = row0 + rowblk * 16 + l16;

    f32x4 acc[12];
#pragma unroll
    for (int t = 0; t < 12; ++t) acc[t] = (f32x4){0.f, 0.f, 0.f, 0.f};

    // this wave's K-half: cols khalf*256 .. +255 (kc = khalf*8 + 0..7)
    const float* xp = x + (size_t)rowW * C_EMB + khalf * 256 + quad * 8;
    const int kb = khalf * 8;
    float4 xr[2][8];
    ld_stage(xp, 0, xr[0]);
    ld_stage(xp, 1, xr[1]);
    mm_stage(xr[0], kb, 0, l16, quad, wt, acc);
    mm_stage(xr[1], kb, 1, l16, quad, wt, acc);

    // merge K-half partials through LDS
    if (khalf == 1) {
#pragma unroll
        for (int t = 0; t < 12; ++t) Red[rowblk][t][lane] = acc[t];
    }
    __syncthreads();
    if (khalf == 0) {
#pragma unroll
        for (int t = 0; t < 12; ++t) {
            f32x4 r = Red[rowblk][t][lane];
#pragma unroll
            for (int i = 0; i < 4; ++i) acc[t][i] += r[i];
        }
        // epilogue: C layout row = quad*4+r, col = l16 per 16-col tile
#pragma unroll
        for (int n = 0; n < 4; ++n)
#pragma unroll
            for (int r = 0; r < 4; ++r) {
                const int row = row0 + rowblk * 16 + quad * 4 + r;
                qout[(size_t)row * HEAD + n * 16 + l16] = f2bf(acc[n][r] * C2);
                kout[(size_t)row * HEAD + n * 16 + l16] = f2bf(acc[4 + n][r]);
                Vsh[n * 16 + l16][rowblk * 16 + quad * 4 + r] = f2bf(acc[8 + n][r]);
            }
    }
    __syncthreads();
    {
        int h  = tid >> 2;
        int tc = (tid & 3) * 8;
        int b  = row0 >> 12;
        int t0 = row0 & (T_SEQ - 1);
        unsigned short* dst = vt + ((size_t)(b * HEAD + h)) * T_SEQ + t0 + tc;
        *(short8*)dst = *(const short8*)&Vsh[h][tc];
    }
}

// stage one V row-chunk (16 cols from sc) phi-swizzled:
// col c bits [s|d|q1 q0|r1 r0] -> position [s|q1 q0|d|r1 r0]
// so PV B-frags are single contiguous b128 reads matching the A-frag k-order.
__device__ __forceinline__ void stage_v(unsigned short (*Vbuf)[72], int sr, int phiA,
                                        short8 v0, short8 v1) {
    *(short4v*)&Vbuf[sr][phiA]      = __builtin_shufflevector(v0, v0, 0, 1, 2, 3);
    *(short4v*)&Vbuf[sr][phiA + 8]  = __builtin_shufflevector(v0, v0, 4, 5, 6, 7);
    *(short4v*)&Vbuf[sr][phiA + 16] = __builtin_shufflevector(v1, v1, 0, 1, 2, 3);
    *(short4v*)&Vbuf[sr][phiA + 24] = __builtin_shufflevector(v1, v1, 4, 5, 6, 7);
}

// ---------------- Attention phase 1: S^T trick, no P LDS round-trip ----------
__global__ __launch_bounds__(256) void attn1_kernel(
    const unsigned short* __restrict__ qb,  // [B*T, 64] pre-scaled
    const unsigned short* __restrict__ kb,  // [B*T, 64]
    const unsigned short* __restrict__ vt,  // [4][64][4096]
    unsigned short* __restrict__ po,        // [1152][64][64] bf16 partials
    float* __restrict__ pl)                 // [1152][64]
{
    __shared__ unsigned short Ks[2][64][72];    // [buf][kpos][h]
    __shared__ unsigned short Vs[2][64][72];    // [buf][h][phi(kpos)]

    const int tid  = threadIdx.x;
    const int wave = tid >> 6;
    const int lane = tid & 63;
    const int l16  = lane & 15;
    const int quad = lane >> 4;

    const int b = blockIdx.x / EPB;
    const int e = blockIdx.x % EPB;
    // decode e -> (qt, c): group g has qt in [8g,8g+8), nc=g+1, base 4g(g+1)
    int g = 0;
#pragma unroll
    for (int gg = 1; gg < 8; ++gg) if (e >= 4 * gg * (gg + 1)) g = gg;
    const int rem = e - 4 * g * (g + 1);
    const int t   = rem / (g + 1);
    const int c   = rem - t * (g + 1);
    const int qt  = 8 * g + t;

    const size_t base = (size_t)b * T_SEQ;
    const int qrow = qt * 64 + wave * 16 + l16;
    short8 aq0 = *(const short8*)(qb + (base + qrow) * HEAD + quad * 8);
    short8 aq1 = *(const short8*)(qb + (base + qrow) * HEAD + 32 + quad * 8);

    float lacc = 0.f;
    f32x4 o[4];
#pragma unroll
    for (int n = 0; n < 4; ++n) o[n] = (f32x4){0.f, 0.f, 0.f, 0.f};

    const int kt0 = c * CHUNK;
    const int np  = min(CHUNK, qt + 1 - kt0);   // 1..8 64-wide iterations

    const int sr   = tid >> 2;            // 0..63
    const int sc   = (tid & 3) * 16;      // 0,16,32,48
    const int phiA = (sc & 32) + ((sc & 16) >> 2);

    short8 kra, krb, vra, vrb;
    {
        const int kbase = kt0 * 64;
        const unsigned short* ksrc = kb + (base + kbase + sr) * HEAD + sc;
        const unsigned short* vsrc = vt + ((size_t)(b * HEAD + sr)) * T_SEQ + kbase + sc;
        kra = *(const short8*)(ksrc);     krb = *(const short8*)(ksrc + 8);
        vra = *(const short8*)(vsrc);     vrb = *(const short8*)(vsrc + 8);
    }
    *(short8*)&Ks[0][sr][sc]     = kra;  *(short8*)&Ks[0][sr][sc + 8] = krb;
    stage_v(Vs[0], sr, phiA, vra, vrb);

    for (int p = 0; p < np; ++p) {
        const int cur = p & 1;
        const int kbase = (kt0 + p) * 64;
        __syncthreads();                 // LDS[cur] ready; prev-iter reads done

        if (p + 1 < np) {                // prefetch next tile into regs
            const int nb = kbase + 64;
            const unsigned short* ksrc = kb + (base + nb + sr) * HEAD + sc;
            const unsigned short* vsrc = vt + ((size_t)(b * HEAD + sr)) * T_SEQ + nb + sc;
            kra = *(const short8*)(ksrc);  krb = *(const short8*)(ksrc + 8);
            vra = *(const short8*)(vsrc);  vrb = *(const short8*)(vsrc + 8);
        }

        // S^T = K.Q^T: lane gets S[q=l16][c = kbase + n*16 + quad*4 + r]
        f32x4 s[4];
#pragma unroll
        for (int n = 0; n < 4; ++n) {
            short8 bk0 = *(const short8*)&Ks[cur][n * 16 + l16][quad * 8];
            short8 bk1 = *(const short8*)&Ks[cur][n * 16 + l16][32 + quad * 8];
            f32x4 accS = (f32x4){0.f, 0.f, 0.f, 0.f};
            accS = __builtin_amdgcn_mfma_f32_16x16x32_bf16(bk0, aq0, accS, 0, 0, 0);
            accS = __builtin_amdgcn_mfma_f32_16x16x32_bf16(bk1, aq1, accS, 0, 0, 0);
            s[n] = accS;
        }

        // P = exp2(S); zero masked cols on the diagonal tile (wave-uniform test)
#pragma unroll
        for (int n = 0; n < 4; ++n)
#pragma unroll
            for (int r = 0; r < 4; ++r)
                s[n][r] = __builtin_amdgcn_exp2f(s[n][r]);

        if (kbase + 64 > qt * 64) {
            const int cb = kbase + quad * 4;
#pragma unroll
            for (int n = 0; n < 4; ++n)
#pragma unroll
                for (int r = 0; r < 4; ++r)
                    if (cb + n * 16 + r > qrow) s[n][r] = 0.f;
        }

#pragma unroll
        for (int n = 0; n < 4; ++n)
            lacc += (s[n][0] + s[n][1]) + (s[n][2] + s[n][3]);

        // PV: pack A-frag locally (k-order matches phi-swizzled V), B = b128
#pragma unroll
        for (int st = 0; st < 2; ++st) {
            int4 ai = make_int4(
                (int)pk2bf(s[2 * st][0],     s[2 * st][1]),
                (int)pk2bf(s[2 * st][2],     s[2 * st][3]),
                (int)pk2bf(s[2 * st + 1][0], s[2 * st + 1][1]),
                (int)pk2bf(s[2 * st + 1][2], s[2 * st + 1][3]));
            short8 af = *(short8*)&ai;
#pragma unroll
            for (int n = 0; n < 4; ++n) {
                short8 bv = *(const short8*)&Vs[cur][n * 16 + l16][32 * st + quad * 8];
                o[n] = __builtin_amdgcn_mfma_f32_16x16x32_bf16(af, bv, o[n], 0, 0, 0);
            }
        }

        if (p + 1 < np) {                // stage next tile into the other buffer
            const int nxt = cur ^ 1;
            *(short8*)&Ks[nxt][sr][sc]     = kra;  *(short8*)&Ks[nxt][sr][sc + 8] = krb;
            stage_v(Vs[nxt], sr, phiA, vra, vrb);
        }
    }

    // reduce l over the quad dimension (q-row = l16 per lane)
    lacc += __shfl_xor(lacc, 16);
    lacc += __shfl_xor(lacc, 32);

    const int pid = blockIdx.x;
#pragma unroll
    for (int n = 0; n < 4; ++n)
#pragma unroll
        for (int r = 0; r < 4; ++r) {
            int lr = wave * 16 + quad * 4 + r;
            po[(size_t)pid * 4096 + lr * 64 + n * 16 + l16] = f2bf(o[n][r]);
        }
    if (quad == 0)
        pl[pid * 64 + wave * 16 + l16] = lacc;
}

// ---------------- Combine: sum <=8 bf16 partials, normalize ----------------
// grid 512 x 256; thread owns 8 output cols (one short8 read per partial).
__global__ __launch_bounds__(256) void combine_kernel(
    const unsigned short* __restrict__ po, const float* __restrict__ pl,
    float* __restrict__ out)
{
    const int gth = blockIdx.x * 256 + threadIdx.x;   // octet index, 131072 total
    const int h8  = gth & 7;
    const int row = gth >> 3;
    const int lr  = row & 63;
    const int qt  = (row >> 6) & 63;
    const int b   = row >> 12;
    const int nc  = (qt >> 3) + 1;
    const int g   = qt >> 3;
    const int rem = qt & 7;
    const int e0  = 4 * g * (g + 1) + rem * (g + 1);
    const int pid0 = b * EPB + e0;

    float l = 0.f;
    float acc[8];
#pragma unroll
    for (int i = 0; i < 8; ++i) acc[i] = 0.f;
    for (int cc = 0; cc < nc; ++cc) {
        l += pl[(pid0 + cc) * 64 + lr];
        short8 p8 = *(const short8*)(po + (size_t)(pid0 + cc) * 4096 + lr * 64 + h8 * 8);
#pragma unroll
        for (int i = 0; i < 8; ++i) acc[i] += bf2f((unsigned short)p8[i]);
    }
    float inv = 1.f / l;
    float4 r0 = make_float4(acc[0] * inv, acc[1] * inv, acc[2] * inv, acc[3] * inv);
    float4 r1 = make_float4(acc[4] * inv, acc[5] * inv, acc[6] * inv, acc[7] * inv);
    float* dst = out + (size_t)gth * 8;
    *(float4*)dst       = r0;
    *(float4*)(dst + 4) = r1;
}

extern "C" void kernel_launch(void* const* d_in, const int* in_sizes, int n_in,
                              void* d_out, int out_size, void* d_ws, size_t ws_size,
                              hipStream_t stream) {
    const float* x  = (const float*)d_in[0];
    const float* Wq = (const float*)d_in[1];
    const float* Wk = (const float*)d_in[2];
    const float* Wv = (const float*)d_in[3];
    float* out = (float*)d_out;

    char* ws = (char*)d_ws;
    unsigned short* qb = (unsigned short*)(ws);                 // 2 MB
    unsigned short* kb = (unsigned short*)(ws + (2u << 20));    // 2 MB
    unsigned short* vt = (unsigned short*)(ws + (4u << 20));    // 2 MB
    unsigned short* wt = (unsigned short*)(ws + (6u << 20));    // 192 KB
    float* pl = (float*)(ws + (6u << 20) + 196608);             // 294912 B
    unsigned short* po = (unsigned short*)(ws + (6u << 20) + 196608 + 294912); // 9.4 MB

    wcvt_kernel<<<dim3(192), dim3(64), 0, stream>>>(Wq, Wk, Wv, wt);
    proj_kernel<<<dim3(512), dim3(256), 0, stream>>>(x, wt, qb, kb, vt);
    attn1_kernel<<<dim3(NBATCH * EPB), dim3(256), 0, stream>>>(qb, kb, vt, po, pl);
    combine_kernel<<<dim3(512), dim3(256), 0, stream>>>(po, pl, out);
}